// Round 1
// baseline (172.304 us; speedup 1.0000x reference)
//
#include <hip/hip_runtime.h>
#include <stdint.h>

// Exact IEEE double mul/add via inline asm: immune to -ffp-contract=fast,
// guaranteeing bit-identical results to the XLA f64 reference (which emits
// separate fmul/fadd, no FMA fusion).
__device__ __forceinline__ double dmul(double a, double b) {
    double d;
    asm("v_mul_f64 %0, %1, %2" : "=v"(d) : "v"(a), "v"(b));
    return d;
}
__device__ __forceinline__ double dadd(double a, double b) {
    double d;
    asm("v_add_f64 %0, %1, %2" : "=v"(d) : "v"(a), "v"(b));
    return d;
}

// Circuit-exact sin on raw f64 bits. Returns raw output bits.
__device__ __forceinline__ uint64_t sin_bits(uint64_t u) {
    const double TWO_OVER_PI = 2.0 / 3.141592653589793;   // folded IEEE double div == Python 2.0/math.pi
    const double PI_OVER_2   = 3.141592653589793 / 2.0;   // exact scaling

    double x = __longlong_as_double((long long)u);

    // q = SpikeFP64Round(x * 2/pi): clear sign, floor(|.|+0.5), reattach sign
    double xq    = dmul(x, TWO_OVER_PI);
    double q_abs = floor(dadd(fabs(xq), 0.5));            // floor/fabs are exact
    uint64_t xqu = (uint64_t)__double_as_longlong(xq);
    bool q_neg   = (xqu >> 63) & 1ull;
    double q     = q_neg ? -q_abs : q_abs;                // preserves -0

    double qp = dmul(q, PI_OVER_2);
    double r  = dadd(x, -qp);                             // x + (-qp)

    // SpikeFP64ExtractMod4 on q's raw bits
    uint64_t qu = (uint64_t)__double_as_longlong(q);
    bool e10 = (qu >> 62) & 1ull;
    bool e0  = (qu >> 52) & 1ull;
    bool m51 = (qu >> 51) & 1ull;
    bool m50 = (qu >> 50) & 1ull;
    bool b0_high = e0 ? m50 : m51;
    bool b1_high = e0 ? m51 : true;
    bool b0 = e10 ? b0_high : e0;
    bool b1 = e10 ? b1_high : false;
    if (q_neg) b1 = b1 ^ b0;

    // Taylor, exact op/sum order of the reference
    double r2 = dmul(r, r);
    double r3 = dmul(r2, r);
    double r5 = dmul(r3, r2);
    double r7 = dmul(r5, r2);
    double sin_r = dadd(dadd(dadd(r, dmul(r3, -1.0 / 6.0)),
                             dmul(r5, 1.0 / 120.0)),
                        dmul(r7, -1.0 / 5040.0));
    double r4 = dmul(r2, r2);
    double r6 = dmul(r4, r2);
    double cos_r = dadd(dadd(dadd(1.0, dmul(r2, -0.5)),
                             dmul(r4, 1.0 / 24.0)),
                        dmul(r6, -1.0 / 720.0));

    double base = b0 ? cos_r : sin_r;
    uint64_t bu = (uint64_t)__double_as_longlong(base);
    uint64_t out_sign = ((bu >> 63) ^ (uint64_t)b1) & 1ull;
    return (bu & 0x7fffffffffffffffull) | (out_sign << 63);
}

__global__ __launch_bounds__(256) void spike_sin_kernel(
        const float4* __restrict__ in, float4* __restrict__ out, int n) {
    int i = blockIdx.x * blockDim.x + threadIdx.x;
    if (i >= n) return;

    const float4* p = in + (size_t)i * 16;

    // Pack 64 MSB-first bit-floats into a uint64 (two 32-bit halves).
    uint32_t hi = 0, lo = 0;
    #pragma unroll
    for (int t = 0; t < 8; ++t) {
        float4 v = p[t];
        hi = (hi << 1) | (uint32_t)(v.x != 0.0f);
        hi = (hi << 1) | (uint32_t)(v.y != 0.0f);
        hi = (hi << 1) | (uint32_t)(v.z != 0.0f);
        hi = (hi << 1) | (uint32_t)(v.w != 0.0f);
    }
    #pragma unroll
    for (int t = 8; t < 16; ++t) {
        float4 v = p[t];
        lo = (lo << 1) | (uint32_t)(v.x != 0.0f);
        lo = (lo << 1) | (uint32_t)(v.y != 0.0f);
        lo = (lo << 1) | (uint32_t)(v.z != 0.0f);
        lo = (lo << 1) | (uint32_t)(v.w != 0.0f);
    }
    uint64_t u = ((uint64_t)hi << 32) | (uint64_t)lo;

    uint64_t ob = sin_bits(u);

    // Unpack MSB-first back to bit-floats.
    uint32_t ohi = (uint32_t)(ob >> 32);
    uint32_t olo = (uint32_t)ob;
    float4* q = out + (size_t)i * 16;
    #pragma unroll
    for (int t = 0; t < 8; ++t) {
        float4 v;
        v.x = (float)((ohi >> (31 - (4 * t + 0))) & 1u);
        v.y = (float)((ohi >> (31 - (4 * t + 1))) & 1u);
        v.z = (float)((ohi >> (31 - (4 * t + 2))) & 1u);
        v.w = (float)((ohi >> (31 - (4 * t + 3))) & 1u);
        q[t] = v;
    }
    #pragma unroll
    for (int t = 0; t < 8; ++t) {
        float4 v;
        v.x = (float)((olo >> (31 - (4 * t + 0))) & 1u);
        v.y = (float)((olo >> (31 - (4 * t + 1))) & 1u);
        v.z = (float)((olo >> (31 - (4 * t + 2))) & 1u);
        v.w = (float)((olo >> (31 - (4 * t + 3))) & 1u);
        q[t + 8] = v;
    }
}

extern "C" void kernel_launch(void* const* d_in, const int* in_sizes, int n_in,
                              void* d_out, int out_size, void* d_ws, size_t ws_size,
                              hipStream_t stream) {
    const float4* in = (const float4*)d_in[0];
    float4* out = (float4*)d_out;
    int n = out_size / 64;  // number of doubles
    int threads = 256;
    int blocks = (n + threads - 1) / threads;
    spike_sin_kernel<<<blocks, threads, 0, stream>>>(in, out, n);
}

// Round 3
// 106.225 us; speedup vs baseline: 1.6221x; 1.6221x over previous
//
#include <hip/hip_runtime.h>
#include <stdint.h>

// Exact IEEE double mul/add via inline asm: immune to -ffp-contract=fast,
// guaranteeing bit-identical results to the XLA f64 reference (which emits
// separate fmul/fadd, no FMA fusion).
__device__ __forceinline__ double dmul(double a, double b) {
    double d;
    asm("v_mul_f64 %0, %1, %2" : "=v"(d) : "v"(a), "v"(b));
    return d;
}
__device__ __forceinline__ double dadd(double a, double b) {
    double d;
    asm("v_add_f64 %0, %1, %2" : "=v"(d) : "v"(a), "v"(b));
    return d;
}

// Circuit-exact sin on raw f64 bits. Returns raw output bits.
__device__ __forceinline__ uint64_t sin_bits(uint64_t u) {
    const double TWO_OVER_PI = 2.0 / 3.141592653589793;   // compile-time IEEE div == Python 2.0/math.pi
    const double PI_OVER_2   = 3.141592653589793 / 2.0;

    double x = __longlong_as_double((long long)u);

    // q = SpikeFP64Round(x * 2/pi): clear sign, floor(|.|+0.5), reattach sign
    double xq    = dmul(x, TWO_OVER_PI);
    double q_abs = floor(dadd(fabs(xq), 0.5));            // floor/fabs are exact
    uint64_t xqu = (uint64_t)__double_as_longlong(xq);
    bool q_neg   = (xqu >> 63) & 1ull;
    double q     = q_neg ? -q_abs : q_abs;                // preserves -0

    double qp = dmul(q, PI_OVER_2);
    double r  = dadd(x, -qp);                             // x + (-qp)

    // SpikeFP64ExtractMod4 on q's raw bits
    uint64_t qu = (uint64_t)__double_as_longlong(q);
    bool e10 = (qu >> 62) & 1ull;
    bool e0  = (qu >> 52) & 1ull;
    bool m51 = (qu >> 51) & 1ull;
    bool m50 = (qu >> 50) & 1ull;
    bool b0_high = e0 ? m50 : m51;
    bool b1_high = e0 ? m51 : true;
    bool b0 = e10 ? b0_high : e0;
    bool b1 = e10 ? b1_high : false;
    if (q_neg) b1 = b1 ^ b0;

    // Taylor, exact op/sum order of the reference
    double r2 = dmul(r, r);
    double r3 = dmul(r2, r);
    double r5 = dmul(r3, r2);
    double r7 = dmul(r5, r2);
    double sin_r = dadd(dadd(dadd(r, dmul(r3, -1.0 / 6.0)),
                             dmul(r5, 1.0 / 120.0)),
                        dmul(r7, -1.0 / 5040.0));
    double r4 = dmul(r2, r2);
    double r6 = dmul(r4, r2);
    double cos_r = dadd(dadd(dadd(1.0, dmul(r2, -0.5)),
                             dmul(r4, 1.0 / 24.0)),
                        dmul(r6, -1.0 / 720.0));

    double base = b0 ? cos_r : sin_r;
    uint64_t bu = (uint64_t)__double_as_longlong(base);
    uint64_t out_sign = ((bu >> 63) ^ (uint64_t)b1) & 1ull;
    return (bu & 0x7fffffffffffffffull) | (out_sign << 63);
}

// Wave-coalesced layout: each wave handles 64 consecutive doubles.
// Gather:  iteration k, lane j reads float j of double k (256 B contiguous
//          per load instruction = 4 full 64B lines). __ballot packs the wave's
//          64 predicates into one wave-uniform uint64 (bit j = float j); the
//          lane==k select (v_cmp + 2x v_cndmask, SGPR src) deposits it into
//          lane k. After 64 iters lane k owns double k's bits.
// Scatter: readlane broadcasts lane k's result; lane j extracts its bit and
//          the wave stores 256 B contiguous — full-line writes, no RMW.
__global__ __launch_bounds__(256) void spike_sin_kernel(
        const float* __restrict__ in, float* __restrict__ out, int n) {
    const int wave = threadIdx.x >> 6;
    const int lane = threadIdx.x & 63;
    const size_t dbase = ((size_t)blockIdx.x * (blockDim.x >> 6) + wave) * 64;
    if (dbase >= (size_t)n) return;   // n is a multiple of 64

    const float* ip = in + dbase * 64;
    uint32_t ulo = 0, uhi = 0;
    #pragma unroll
    for (int k = 0; k < 64; ++k) {
        float f = ip[(size_t)k * 64 + lane];
        uint64_t m = __ballot(f != 0.0f);              // bit j = float j of double k
        uint32_t mlo = (uint32_t)m;
        uint32_t mhi = (uint32_t)(m >> 32);
        if (lane == k) { ulo = mlo; uhi = mhi; }       // deposit into lane k
    }
    // mask bit j = float j = IEEE bit (63-j)  ->  bit-reverse to IEEE order
    uint64_t u = __brevll(((uint64_t)uhi << 32) | ulo);

    uint64_t ob = sin_bits(u);

    // rev bit j = IEEE bit (63-j) = float j of the output
    uint64_t rev = __brevll(ob);
    uint32_t rlo = (uint32_t)rev, rhi = (uint32_t)(rev >> 32);

    float* op = out + dbase * 64;
    #pragma unroll
    for (int k = 0; k < 64; ++k) {
        uint32_t slo = __builtin_amdgcn_readlane(rlo, k);
        uint32_t shi = __builtin_amdgcn_readlane(rhi, k);
        uint32_t w   = (lane & 32) ? shi : slo;
        uint32_t bit = (w >> (lane & 31)) & 1u;
        op[(size_t)k * 64 + lane] = (float)bit;
    }
}

extern "C" void kernel_launch(void* const* d_in, const int* in_sizes, int n_in,
                              void* d_out, int out_size, void* d_ws, size_t ws_size,
                              hipStream_t stream) {
    const float* in = (const float*)d_in[0];
    float* out = (float*)d_out;
    int n = out_size / 64;                 // number of doubles (1024*1024)
    int threads = 256;                     // 4 waves/block, 256 doubles/block
    int doubles_per_block = (threads / 64) * 64;
    int blocks = (n + doubles_per_block - 1) / doubles_per_block;
    spike_sin_kernel<<<blocks, threads, 0, stream>>>(in, out, n);
}

// Round 5
// 81.192 us; speedup vs baseline: 2.1222x; 1.3083x over previous
//
#include <hip/hip_runtime.h>
#include <stdint.h>

typedef float f32x4 __attribute__((ext_vector_type(4)));  // clang vector: valid for nontemporal builtins

// Exact IEEE double mul/add via inline asm: immune to -ffp-contract=fast,
// guaranteeing bit-identical results to the XLA f64 reference (which emits
// separate fmul/fadd, no FMA fusion).
__device__ __forceinline__ double dmul(double a, double b) {
    double d;
    asm("v_mul_f64 %0, %1, %2" : "=v"(d) : "v"(a), "v"(b));
    return d;
}
__device__ __forceinline__ double dadd(double a, double b) {
    double d;
    asm("v_add_f64 %0, %1, %2" : "=v"(d) : "v"(a), "v"(b));
    return d;
}

// Circuit-exact sin on raw f64 bits. Returns raw output bits.
__device__ __forceinline__ uint64_t sin_bits(uint64_t u) {
    const double TWO_OVER_PI = 2.0 / 3.141592653589793;   // compile-time IEEE div == Python 2.0/math.pi
    const double PI_OVER_2   = 3.141592653589793 / 2.0;

    double x = __longlong_as_double((long long)u);

    // q = SpikeFP64Round(x * 2/pi): clear sign, floor(|.|+0.5), reattach sign
    double xq    = dmul(x, TWO_OVER_PI);
    double q_abs = floor(dadd(fabs(xq), 0.5));            // floor/fabs are exact
    uint64_t xqu = (uint64_t)__double_as_longlong(xq);
    bool q_neg   = (xqu >> 63) & 1ull;
    double q     = q_neg ? -q_abs : q_abs;                // preserves -0

    double qp = dmul(q, PI_OVER_2);
    double r  = dadd(x, -qp);                             // x + (-qp)

    // SpikeFP64ExtractMod4 on q's raw bits
    uint64_t qu = (uint64_t)__double_as_longlong(q);
    bool e10 = (qu >> 62) & 1ull;
    bool e0  = (qu >> 52) & 1ull;
    bool m51 = (qu >> 51) & 1ull;
    bool m50 = (qu >> 50) & 1ull;
    bool b0_high = e0 ? m50 : m51;
    bool b1_high = e0 ? m51 : true;
    bool b0 = e10 ? b0_high : e0;
    bool b1 = e10 ? b1_high : false;
    if (q_neg) b1 = b1 ^ b0;

    // Taylor, exact op/sum order of the reference
    double r2 = dmul(r, r);
    double r3 = dmul(r2, r);
    double r5 = dmul(r3, r2);
    double r7 = dmul(r5, r2);
    double sin_r = dadd(dadd(dadd(r, dmul(r3, -1.0 / 6.0)),
                             dmul(r5, 1.0 / 120.0)),
                        dmul(r7, -1.0 / 5040.0));
    double r4 = dmul(r2, r2);
    double r6 = dmul(r4, r2);
    double cos_r = dadd(dadd(dadd(1.0, dmul(r2, -0.5)),
                             dmul(r4, 1.0 / 24.0)),
                        dmul(r6, -1.0 / 720.0));

    double base = b0 ? cos_r : sin_r;
    uint64_t bu = (uint64_t)__double_as_longlong(base);
    uint64_t out_sign = ((bu >> 63) ^ (uint64_t)b1) & 1ull;
    return (bu & 0x7fffffffffffffffull) | (out_sign << 63);
}

// Wave-coalesced layout: each wave handles 64 consecutive doubles (16 KB in,
// 16 KB out).
// Gather:  iteration k, lane j reads float j of double k (256 B contiguous =
//          4 full 64B lines per load). __ballot packs the wave's predicates
//          into one wave-uniform uint64 (bit j = float j); lane==k select
//          deposits it. Loads are CACHEABLE on purpose: with NT output
//          stores, the 256 MB input can stay L3-resident across replays.
// Scatter: iteration k, lane j emits float4 = floats k*256+j*4..+3, i.e.
//          float-quad fq=j&15 of double d=k*4+(j>>4). Two __shfl fetch that
//          double's bits (src uniform per 16-lane group); 16 B/lane NT
//          stores = full-line, no-allocate (keep L3 free for the input).
__global__ __launch_bounds__(256) void spike_sin_kernel(
        const float* __restrict__ in, float* __restrict__ out, int n) {
    const int wave = threadIdx.x >> 6;
    const int lane = threadIdx.x & 63;
    const size_t dbase = ((size_t)blockIdx.x * (blockDim.x >> 6) + wave) * 64;
    if (dbase >= (size_t)n) return;   // n is a multiple of 64

    const float* ip = in + dbase * 64;
    uint32_t ulo = 0, uhi = 0;
    #pragma unroll
    for (int k = 0; k < 64; ++k) {
        float f = ip[(size_t)k * 64 + lane];
        uint64_t m = __ballot(f != 0.0f);              // bit j = float j of double k
        uint32_t mlo = (uint32_t)m;
        uint32_t mhi = (uint32_t)(m >> 32);
        if (lane == k) { ulo = mlo; uhi = mhi; }       // deposit into lane k
    }
    // mask bit j = float j = IEEE bit (63-j)  ->  bit-reverse to IEEE order
    uint64_t u = __brevll(((uint64_t)uhi << 32) | ulo);

    uint64_t ob = sin_bits(u);

    // rev bit f = IEEE bit (63-f) = float f of the output (per lane's double)
    uint64_t rev = __brevll(ob);
    uint32_t rlo = (uint32_t)rev, rhi = (uint32_t)(rev >> 32);

    f32x4* op4 = (f32x4*)(out + dbase * 64);
    const int fq = lane & 15;          // float-quad within the double
    const int grp = lane >> 4;         // which of 4 doubles this lane serves
    const int sh = (fq & 7) * 4;
    #pragma unroll
    for (int k = 0; k < 16; ++k) {
        int src = k * 4 + grp;                      // owner lane of double d
        uint32_t slo = __shfl(rlo, src);
        uint32_t shi = __shfl(rhi, src);
        uint32_t w = (fq < 8) ? slo : shi;
        f32x4 v;
        v.x = (float)((w >> (sh + 0)) & 1u);
        v.y = (float)((w >> (sh + 1)) & 1u);
        v.z = (float)((w >> (sh + 2)) & 1u);
        v.w = (float)((w >> (sh + 3)) & 1u);
        __builtin_nontemporal_store(v, op4 + k * 64 + lane);
    }
}

extern "C" void kernel_launch(void* const* d_in, const int* in_sizes, int n_in,
                              void* d_out, int out_size, void* d_ws, size_t ws_size,
                              hipStream_t stream) {
    const float* in = (const float*)d_in[0];
    float* out = (float*)d_out;
    int n = out_size / 64;                 // number of doubles (1024*1024)
    int threads = 256;                     // 4 waves/block, 256 doubles/block
    int doubles_per_block = (threads / 64) * 64;
    int blocks = (n + doubles_per_block - 1) / doubles_per_block;
    spike_sin_kernel<<<blocks, threads, 0, stream>>>(in, out, n);
}